// Round 3
// baseline (297.028 us; speedup 1.0000x reference)
//
#include <hip/hip_runtime.h>

#define SCALE 0.17677669529663687f  // 1/sqrt(32)
#define PSTR 513                    // padded s_p row stride (bank spread)

// ---------------------------------------------------------------------------
// One block per query row i. 512 blocks x 512 thr (8 waves), ~26 KB LDS ->
// 4 blocks/CU (thread-capped) = 32 waves/CU target.
//
// Prologue: q_s = (x[i]@Wq)*SCALE;
//   s_qc[c*16+h]   = sum_d q_s[h*32+d]*We[c*256+h*32+d]   (e-coef)
//   s_qc[c*16+8+h] = sum_d q_s[h*32+d]*Wk[c*256+h*32+d]   (x-coef)
// P1 (thread=j): logit[h][j] = sum_c e[i,j,c]*qce[c,h] + x[j,c]*qcx[c,h]
//    coef reads vectorized as float4 (4x fewer LDS instrs than scalar).
// P2: softmax per head (wave n owns head n); logits pulled to regs, barrier,
//    then normalized probs written TRANSPOSED back into s_p ([j][8] alias).
// P3 (lane=c, wave owns 64 j): ae/px partials -> LDS atomicAdd.
// Epilogue: emb[nd] = sum_c ae[n,c]We[c,nd] + px[n,c]Wv[c,nd]; out = emb@Wo+bo
//    (scratch aliased into s_p, probs dead by then).
// ---------------------------------------------------------------------------
__global__ __launch_bounds__(512, 8) void fused_kernel(
    const float* __restrict__ e, const float* __restrict__ x,
    const float* __restrict__ Wq, const float* __restrict__ Wk,
    const float* __restrict__ We, const float* __restrict__ Wv,
    const float* __restrict__ Wo, const float* __restrict__ bo,
    float* __restrict__ out) {
  const int t = threadIdx.x, i = blockIdx.x;
  __shared__ float s_x[64];
  __shared__ __align__(16) float s_q[256];
  __shared__ __align__(16) float s_qc[1024];     //  4 KB coefs
  __shared__ __align__(16) float s_p[8 * PSTR];  // 16.4 KB: logits -> probs[j][8] -> scratch
  __shared__ __align__(16) float s_ae[512];
  __shared__ __align__(16) float s_px[512];

  // ---- init + prologue
  s_ae[t] = 0.f; s_px[t] = 0.f;
  if (t < 64) s_x[t] = x[i * 64 + t];
  __syncthreads();
  if (t < 256) {
    float a = 0;
#pragma unroll 8
    for (int c = 0; c < 64; ++c) a += s_x[c] * Wq[c * 256 + t];
    s_q[t] = a * SCALE;
  }
  __syncthreads();
  {
    const int c = t >> 3, h = t & 7;
    const float4* wer = (const float4*)(We + c * 256 + h * 32);
    const float4* wkr = (const float4*)(Wk + c * 256 + h * 32);
    const float4* qr = (const float4*)(s_q + h * 32);
    float se = 0, sk = 0;
#pragma unroll
    for (int u = 0; u < 8; ++u) {
      float4 w1 = wer[u], w2 = wkr[u], qv = qr[u];
      se += qv.x * w1.x + qv.y * w1.y + qv.z * w1.z + qv.w * w1.w;
      sk += qv.x * w2.x + qv.y * w2.y + qv.z * w2.z + qv.w * w2.w;
    }
    s_qc[c * 16 + h] = se;
    s_qc[c * 16 + 8 + h] = sk;
  }
  __syncthreads();

  // ---- Phase 1: one j per thread; coefs via float4 broadcast (uniform addrs)
  {
    const int j = t;
    const float4* erow = (const float4*)(e + (size_t)(i * 512 + j) * 64);
    const float4* xrow = (const float4*)(x + j * 64);
    float acc[8];
#pragma unroll
    for (int h = 0; h < 8; ++h) acc[h] = 0.f;
#pragma unroll 2
    for (int c4 = 0; c4 < 16; ++c4) {
      float4 E = erow[c4];
      float4 X = xrow[c4];
      const float4* qcv = (const float4*)(s_qc + c4 * 64);  // 4 channels x 4 float4
#define CH(Ec, Xc, B)                                                   \
  { float4 ce0 = qcv[B], ce1 = qcv[(B) + 1];                            \
    float4 cx0 = qcv[(B) + 2], cx1 = qcv[(B) + 3];                      \
    acc[0] += Ec * ce0.x + Xc * cx0.x; acc[1] += Ec * ce0.y + Xc * cx0.y; \
    acc[2] += Ec * ce0.z + Xc * cx0.z; acc[3] += Ec * ce0.w + Xc * cx0.w; \
    acc[4] += Ec * ce1.x + Xc * cx1.x; acc[5] += Ec * ce1.y + Xc * cx1.y; \
    acc[6] += Ec * ce1.z + Xc * cx1.z; acc[7] += Ec * ce1.w + Xc * cx1.w; }
      CH(E.x, X.x, 0) CH(E.y, X.y, 4) CH(E.z, X.z, 8) CH(E.w, X.w, 12)
#undef CH
    }
#pragma unroll
    for (int h = 0; h < 8; ++h) s_p[h * PSTR + j] = acc[h];
  }
  __syncthreads();

  // ---- Phase 2: softmax per head (wave n = head n); probs rewritten into s_p
  {
    const int n = t >> 6, l64 = t & 63;
    float lv[8];
    float m = -1e30f;
#pragma unroll
    for (int u = 0; u < 8; ++u) {
      lv[u] = s_p[n * PSTR + l64 + u * 64];
      m = fmaxf(m, lv[u]);
    }
#pragma unroll
    for (int off = 32; off; off >>= 1) m = fmaxf(m, __shfl_xor(m, off, 64));
    float sum = 0;
#pragma unroll
    for (int u = 0; u < 8; ++u) {
      lv[u] = __expf(lv[u] - m);
      sum += lv[u];
    }
#pragma unroll
    for (int off = 32; off; off >>= 1) sum += __shfl_xor(sum, off, 64);
    const float inv = 1.0f / sum;
    __syncthreads();  // all logit reads done -> safe to overwrite s_p with probs
#pragma unroll
    for (int u = 0; u < 8; ++u) s_p[(l64 + u * 64) * 8 + n] = lv[u] * inv;
  }
  __syncthreads();

  // ---- Phase 3: lane=c, wave w owns j in [w*64, w*64+64)
  {
    const int lane = t & 63, w = t >> 6;
    float ae[8], px[8];
#pragma unroll
    for (int h = 0; h < 8; ++h) { ae[h] = 0.f; px[h] = 0.f; }
    const float* ep = e + (size_t)i * 32768 + (size_t)w * 4096 + lane;
    const float* xp = x + w * 4096 + lane;
#pragma unroll 4
    for (int jj = 0; jj < 64; ++jj) {
      const int j = w * 64 + jj;
      float ev = ep[jj * 64];          // coalesced 256B/wave
      float xv = xp[jj * 64];
      const float4* pt = (const float4*)(s_p + j * 8);  // uniform -> broadcast
      float4 p0 = pt[0], p1 = pt[1];
      ae[0] += p0.x * ev; ae[1] += p0.y * ev; ae[2] += p0.z * ev; ae[3] += p0.w * ev;
      ae[4] += p1.x * ev; ae[5] += p1.y * ev; ae[6] += p1.z * ev; ae[7] += p1.w * ev;
      px[0] += p0.x * xv; px[1] += p0.y * xv; px[2] += p0.z * xv; px[3] += p0.w * xv;
      px[4] += p1.x * xv; px[5] += p1.y * xv; px[6] += p1.z * xv; px[7] += p1.w * xv;
    }
#pragma unroll
    for (int h = 0; h < 8; ++h) {
      atomicAdd(&s_ae[h * 64 + lane], ae[h]);  // ds_add_f32, disjoint addrs in-wave
      atomicAdd(&s_px[h * 64 + lane], px[h]);
    }
  }
  __syncthreads();

  // ---- Epilogue (scratch aliases the now-dead s_p)
  float* s_eb  = s_p;         // 512 floats: partial emb
  float* s_emb = s_p + 512;   // 256 floats
  float* s_op  = s_p + 1024;  // 512 floats
  {
    const int nd = t & 255, ch = t >> 8, hn = nd >> 5;
    float emb = 0;
    const int cb = ch * 32;
#pragma unroll 8
    for (int c = cb; c < cb + 32; ++c)
      emb += s_ae[hn * 64 + c] * We[c * 256 + nd] + s_px[hn * 64 + c] * Wv[c * 256 + nd];
    s_eb[ch * 256 + nd] = emb;
  }
  __syncthreads();
  if (t < 256) s_emb[t] = s_eb[t] + s_eb[256 + t];
  __syncthreads();
  {
    const int o = t & 63, mc = t >> 6;
    float oo = 0;
#pragma unroll 8
    for (int m2 = mc * 32; m2 < mc * 32 + 32; ++m2) oo += s_emb[m2] * Wo[m2 * 64 + o];
    s_op[mc * 64 + o] = oo;
  }
  __syncthreads();
  if (t < 64) {
    float r = bo[t];
#pragma unroll
    for (int w2 = 0; w2 < 8; ++w2) r += s_op[w2 * 64 + t];
    out[i * 64 + t] = r;
  }
}

extern "C" void kernel_launch(void* const* d_in, const int* in_sizes, int n_in,
                              void* d_out, int out_size, void* d_ws, size_t ws_size,
                              hipStream_t stream) {
  const float* x  = (const float*)d_in[0];
  const float* e  = (const float*)d_in[1];
  const float* Wq = (const float*)d_in[2];
  const float* Wk = (const float*)d_in[3];
  const float* Wv = (const float*)d_in[4];
  const float* We = (const float*)d_in[5];
  const float* Wo = (const float*)d_in[6];
  const float* bo = (const float*)d_in[7];
  float* out = (float*)d_out;

  hipLaunchKernelGGL(fused_kernel, dim3(512), dim3(512), 0, stream,
                     e, x, Wq, Wk, We, Wv, Wo, bo, out);
}

// Round 5
// 190.251 us; speedup vs baseline: 1.5612x; 1.5612x over previous
//
#include <hip/hip_runtime.h>

#define SCALE 0.17677669529663687f  // 1/sqrt(32)
#define PSTR 513                    // padded s_p row stride (bank spread)

// ---------------------------------------------------------------------------
// One block per query row i. 512 blocks x 512 thr (8 waves), ~26 KB LDS ->
// 4 blocks/CU (thread-capped) = 32 waves/CU.
// __launch_bounds__(512, 4): allocator floor 4 waves/EU -> VGPR cap 64
// (measured: (512,8)/(1024,8) clamp to 32 VGPR and spill ~350 MB to scratch).
//
// Prologue: q_s = (x[i]@Wq)*SCALE;
//   s_qc[c*16+h]   = sum_d q_s[h*32+d]*We[c*256+h*32+d]   (e-coef)
//   s_qc[c*16+8+h] = sum_d q_s[h*32+d]*Wk[c*256+h*32+d]   (x-coef)
// P1 (thread=j): logit[h][j] = sum_c e[i,j,c]*qce[c,h] + x[j,c]*qcx[c,h]
//    coef reads vectorized as float4 (4x fewer LDS instrs than scalar).
// P2: softmax per head (wave n owns head n); logits pulled to regs, barrier,
//    then normalized probs written TRANSPOSED back into s_p ([j][8] alias).
// P3 (lane=c, wave owns 64 j): ae/px partials -> LDS atomicAdd.
// Epilogue: emb[nd] = sum_c ae[n,c]We[c,nd] + px[n,c]Wv[c,nd]; out = emb@Wo+bo
//    (scratch aliased into s_p, probs dead by then).
// ---------------------------------------------------------------------------
__global__ __launch_bounds__(512, 4) void fused_kernel(
    const float* __restrict__ e, const float* __restrict__ x,
    const float* __restrict__ Wq, const float* __restrict__ Wk,
    const float* __restrict__ We, const float* __restrict__ Wv,
    const float* __restrict__ Wo, const float* __restrict__ bo,
    float* __restrict__ out) {
  const int t = threadIdx.x, i = blockIdx.x;
  __shared__ float s_x[64];
  __shared__ __align__(16) float s_q[256];
  __shared__ __align__(16) float s_qc[1024];     //  4 KB coefs
  __shared__ __align__(16) float s_p[8 * PSTR];  // 16.4 KB: logits -> probs[j][8] -> scratch
  __shared__ __align__(16) float s_ae[512];
  __shared__ __align__(16) float s_px[512];

  // ---- init + prologue
  s_ae[t] = 0.f; s_px[t] = 0.f;
  if (t < 64) s_x[t] = x[i * 64 + t];
  __syncthreads();
  if (t < 256) {
    float a = 0;
#pragma unroll 8
    for (int c = 0; c < 64; ++c) a += s_x[c] * Wq[c * 256 + t];
    s_q[t] = a * SCALE;
  }
  __syncthreads();
  {
    const int c = t >> 3, h = t & 7;
    const float4* wer = (const float4*)(We + c * 256 + h * 32);
    const float4* wkr = (const float4*)(Wk + c * 256 + h * 32);
    const float4* qr = (const float4*)(s_q + h * 32);
    float se = 0, sk = 0;
#pragma unroll
    for (int u = 0; u < 8; ++u) {
      float4 w1 = wer[u], w2 = wkr[u], qv = qr[u];
      se += qv.x * w1.x + qv.y * w1.y + qv.z * w1.z + qv.w * w1.w;
      sk += qv.x * w2.x + qv.y * w2.y + qv.z * w2.z + qv.w * w2.w;
    }
    s_qc[c * 16 + h] = se;
    s_qc[c * 16 + 8 + h] = sk;
  }
  __syncthreads();

  // ---- Phase 1: one j per thread; coefs via float4 broadcast (uniform addrs)
  {
    const int j = t;
    const float4* erow = (const float4*)(e + (size_t)(i * 512 + j) * 64);
    const float4* xrow = (const float4*)(x + j * 64);
    float acc[8];
#pragma unroll
    for (int h = 0; h < 8; ++h) acc[h] = 0.f;
#pragma unroll 2
    for (int c4 = 0; c4 < 16; ++c4) {
      float4 E = erow[c4];
      float4 X = xrow[c4];
      const float4* qcv = (const float4*)(s_qc + c4 * 64);  // 4 channels x 4 float4
#define CH(Ec, Xc, B)                                                   \
  { float4 ce0 = qcv[B], ce1 = qcv[(B) + 1];                            \
    float4 cx0 = qcv[(B) + 2], cx1 = qcv[(B) + 3];                      \
    acc[0] += Ec * ce0.x + Xc * cx0.x; acc[1] += Ec * ce0.y + Xc * cx0.y; \
    acc[2] += Ec * ce0.z + Xc * cx0.z; acc[3] += Ec * ce0.w + Xc * cx0.w; \
    acc[4] += Ec * ce1.x + Xc * cx1.x; acc[5] += Ec * ce1.y + Xc * cx1.y; \
    acc[6] += Ec * ce1.z + Xc * cx1.z; acc[7] += Ec * ce1.w + Xc * cx1.w; }
      CH(E.x, X.x, 0) CH(E.y, X.y, 4) CH(E.z, X.z, 8) CH(E.w, X.w, 12)
#undef CH
    }
#pragma unroll
    for (int h = 0; h < 8; ++h) s_p[h * PSTR + j] = acc[h];
  }
  __syncthreads();

  // ---- Phase 2: softmax per head (wave n = head n); probs rewritten into s_p
  {
    const int n = t >> 6, l64 = t & 63;
    float lv[8];
    float m = -1e30f;
#pragma unroll
    for (int u = 0; u < 8; ++u) {
      lv[u] = s_p[n * PSTR + l64 + u * 64];
      m = fmaxf(m, lv[u]);
    }
#pragma unroll
    for (int off = 32; off; off >>= 1) m = fmaxf(m, __shfl_xor(m, off, 64));
    float sum = 0;
#pragma unroll
    for (int u = 0; u < 8; ++u) {
      lv[u] = __expf(lv[u] - m);
      sum += lv[u];
    }
#pragma unroll
    for (int off = 32; off; off >>= 1) sum += __shfl_xor(sum, off, 64);
    const float inv = 1.0f / sum;
    __syncthreads();  // all logit reads done -> safe to overwrite s_p with probs
#pragma unroll
    for (int u = 0; u < 8; ++u) s_p[(l64 + u * 64) * 8 + n] = lv[u] * inv;
  }
  __syncthreads();

  // ---- Phase 3: lane=c, wave w owns j in [w*64, w*64+64)
  {
    const int lane = t & 63, w = t >> 6;
    float ae[8], px[8];
#pragma unroll
    for (int h = 0; h < 8; ++h) { ae[h] = 0.f; px[h] = 0.f; }
    const float* ep = e + (size_t)i * 32768 + (size_t)w * 4096 + lane;
    const float* xp = x + w * 4096 + lane;
#pragma unroll 4
    for (int jj = 0; jj < 64; ++jj) {
      const int j = w * 64 + jj;
      float ev = ep[jj * 64];          // coalesced 256B/wave
      float xv = xp[jj * 64];
      const float4* pt = (const float4*)(s_p + j * 8);  // uniform -> broadcast
      float4 p0 = pt[0], p1 = pt[1];
      ae[0] += p0.x * ev; ae[1] += p0.y * ev; ae[2] += p0.z * ev; ae[3] += p0.w * ev;
      ae[4] += p1.x * ev; ae[5] += p1.y * ev; ae[6] += p1.z * ev; ae[7] += p1.w * ev;
      px[0] += p0.x * xv; px[1] += p0.y * xv; px[2] += p0.z * xv; px[3] += p0.w * xv;
      px[4] += p1.x * xv; px[5] += p1.y * xv; px[6] += p1.z * xv; px[7] += p1.w * xv;
    }
#pragma unroll
    for (int h = 0; h < 8; ++h) {
      atomicAdd(&s_ae[h * 64 + lane], ae[h]);  // ds_add_f32, disjoint addrs in-wave
      atomicAdd(&s_px[h * 64 + lane], px[h]);
    }
  }
  __syncthreads();

  // ---- Epilogue (scratch aliases the now-dead s_p)
  float* s_eb  = s_p;         // 512 floats: partial emb
  float* s_emb = s_p + 512;   // 256 floats
  float* s_op  = s_p + 1024;  // 512 floats
  {
    const int nd = t & 255, ch = t >> 8, hn = nd >> 5;
    float emb = 0;
    const int cb = ch * 32;
#pragma unroll 8
    for (int c = cb; c < cb + 32; ++c)
      emb += s_ae[hn * 64 + c] * We[c * 256 + nd] + s_px[hn * 64 + c] * Wv[c * 256 + nd];
    s_eb[ch * 256 + nd] = emb;
  }
  __syncthreads();
  if (t < 256) s_emb[t] = s_eb[t] + s_eb[256 + t];
  __syncthreads();
  {
    const int o = t & 63, mc = t >> 6;
    float oo = 0;
#pragma unroll 8
    for (int m2 = mc * 32; m2 < mc * 32 + 32; ++m2) oo += s_emb[m2] * Wo[m2 * 64 + o];
    s_op[mc * 64 + o] = oo;
  }
  __syncthreads();
  if (t < 64) {
    float r = bo[t];
#pragma unroll
    for (int w2 = 0; w2 < 8; ++w2) r += s_op[w2 * 64 + t];
    out[i * 64 + t] = r;
  }
}

extern "C" void kernel_launch(void* const* d_in, const int* in_sizes, int n_in,
                              void* d_out, int out_size, void* d_ws, size_t ws_size,
                              hipStream_t stream) {
  const float* x  = (const float*)d_in[0];
  const float* e  = (const float*)d_in[1];
  const float* Wq = (const float*)d_in[2];
  const float* Wk = (const float*)d_in[3];
  const float* Wv = (const float*)d_in[4];
  const float* We = (const float*)d_in[5];
  const float* Wo = (const float*)d_in[6];
  const float* bo = (const float*)d_in[7];
  float* out = (float*)d_out;

  hipLaunchKernelGGL(fused_kernel, dim3(512), dim3(512), 0, stream,
                     e, x, Wq, Wk, We, Wv, Wo, bo, out);
}

// Round 6
// 184.646 us; speedup vs baseline: 1.6086x; 1.0304x over previous
//
#include <hip/hip_runtime.h>

#define SCALE 0.17677669529663687f  // 1/sqrt(32)
#define PSTR 513                    // padded logit row stride

// ---------------------------------------------------------------------------
// Grid 1024 = (row i) x (head-group hg). Each block: 512 thr (8 waves),
// handles 4 heads -> 4 blocks/CU = 32 waves/CU (round-0..5 grid of 512 blocks
// capped the machine at 2 blocks/CU = 50% occupancy; grid was the binding
// constraint, not LDS).
//
// Prologue: q for our 4 heads; coefs s_qc[c*8 + which*4 + hl]
//   which=0: e-coef (q.We row), which=1: x-coef (q.Wk row)
// P1 (thread=j): acc[4] = logits for local heads; float4 coef broadcast
//   (acc[4]+8 coefs fits 64 VGPR; the acc[8]+16-coef variant spilled 29 MB)
// P2: wave w: head n=w>>1, j-half jh=w&1; butterfly max/sum + 2-wave combine;
//   unnormalized probs transposed into s_p alias [j][4]; inv folded post-P3.
// P3: lane=c, wave owns 64 j; ae/px[4] -> LDS atomicAdd.
// Epilogue: emb for our 128 dims; out partial -> global atomicAdd
//   (out zeroed by hipMemsetAsync; bo added by hg==0 block only).
// ---------------------------------------------------------------------------
__global__ __launch_bounds__(512, 4) void fused_kernel(
    const float* __restrict__ e, const float* __restrict__ x,
    const float* __restrict__ Wq, const float* __restrict__ Wk,
    const float* __restrict__ We, const float* __restrict__ Wv,
    const float* __restrict__ Wo, const float* __restrict__ bo,
    float* __restrict__ out) {
  const int t = threadIdx.x;
  const int i = blockIdx.x >> 1;   // query row
  const int hg = blockIdx.x & 1;   // head-group: global heads hg*4 .. hg*4+3
  const int lane = t & 63, w = t >> 6;

  __shared__ float s_x[64];
  __shared__ __align__(16) float s_q[128];       // q, our 4 heads
  __shared__ __align__(16) float s_qc[512];      // 2 KB coefs [c][{e:4,x:4}]
  __shared__ __align__(16) float s_p[4 * PSTR];  // 8.2 KB: logits -> probs[j][4] -> scratch
  __shared__ float s_red[8], s_red2[8], s_inv[4];
  __shared__ __align__(16) float s_ae[256];
  __shared__ __align__(16) float s_px[256];

  // ---- init + prologue
  if (t < 256) s_ae[t] = 0.f;
  else if (t < 512) s_px[t - 256] = 0.f;
  if (t < 64) s_x[t] = x[i * 64 + t];
  __syncthreads();
  if (t < 128) {  // q for dims hg*128 .. hg*128+127
    const int d = hg * 128 + t;
    float a = 0;
#pragma unroll 8
    for (int c = 0; c < 64; ++c) a += s_x[c] * Wq[c * 256 + d];
    s_q[t] = a * SCALE;
  }
  __syncthreads();
  {  // coefs: c = t>>3, which = (t&7)>>2, hl = t&3
    const int c = t >> 3, hv = t & 7, which = hv >> 2, hl = hv & 3;
    const float* W = which ? Wk : We;
    const float4* wr = (const float4*)(W + c * 256 + (hg * 4 + hl) * 32);
    const float4* qr = (const float4*)(s_q + hl * 32);
    float s = 0;
#pragma unroll
    for (int u = 0; u < 8; ++u) {
      float4 wv = wr[u], qv = qr[u];
      s += qv.x * wv.x + qv.y * wv.y + qv.z * wv.z + qv.w * wv.w;
    }
    s_qc[c * 8 + which * 4 + hl] = s;
  }
  __syncthreads();

  // ---- Phase 1: one j per thread; 4 local heads
  {
    const int j = t;
    const float4* erow = (const float4*)(e + (size_t)(i * 512 + j) * 64);
    const float4* xrow = (const float4*)(x + j * 64);
    float acc[4] = {0.f, 0.f, 0.f, 0.f};
#pragma unroll 4
    for (int c4 = 0; c4 < 16; ++c4) {
      float4 E = erow[c4];
      float4 X = xrow[c4];
      const float4* qcv = (const float4*)(s_qc + c4 * 32);  // 4 channels x {ce,cx}
#define CH(Ec, Xc, B)                                               \
  { float4 ce = qcv[B], cx = qcv[(B) + 1];                          \
    acc[0] += Ec * ce.x + Xc * cx.x; acc[1] += Ec * ce.y + Xc * cx.y; \
    acc[2] += Ec * ce.z + Xc * cx.z; acc[3] += Ec * ce.w + Xc * cx.w; }
      CH(E.x, X.x, 0) CH(E.y, X.y, 2) CH(E.z, X.z, 4) CH(E.w, X.w, 6)
#undef CH
    }
#pragma unroll
    for (int hl = 0; hl < 4; ++hl) s_p[hl * PSTR + j] = acc[hl];
  }
  __syncthreads();

  // ---- Phase 2: wave w: head n = w>>1, j-half jh = w&1 (256 j each)
  {
    const int n = w >> 1, jh = w & 1;
    const int jb = jh * 256 + lane;
    float lv[4];
    float m = -1e30f;
#pragma unroll
    for (int u = 0; u < 4; ++u) {
      lv[u] = s_p[n * PSTR + jb + u * 64];
      m = fmaxf(m, lv[u]);
    }
#pragma unroll
    for (int off = 32; off; off >>= 1) m = fmaxf(m, __shfl_xor(m, off, 64));
    if (lane == 0) s_red[w] = m;
    __syncthreads();  // all logit reads done; max partials visible
    const float M = fmaxf(s_red[n * 2], s_red[n * 2 + 1]);
    float sum = 0;
#pragma unroll
    for (int u = 0; u < 4; ++u) {
      lv[u] = __expf(lv[u] - M);
      sum += lv[u];
      s_p[(jb + u * 64) * 4 + n] = lv[u];  // unnormalized prob, transposed [j][4]
    }
#pragma unroll
    for (int off = 32; off; off >>= 1) sum += __shfl_xor(sum, off, 64);
    if (lane == 0) s_red2[w] = sum;
  }
  __syncthreads();
  if (t < 4) s_inv[t] = 1.0f / (s_red2[t * 2] + s_red2[t * 2 + 1]);
  // (s_inv consumed only after P3's closing barrier)

  // ---- Phase 3: lane=c, wave w owns j in [w*64, w*64+64)
  {
    float ae[4] = {0.f, 0.f, 0.f, 0.f}, px[4] = {0.f, 0.f, 0.f, 0.f};
    const float* ep = e + (size_t)i * 32768 + w * 4096 + lane;
    const float* xp = x + w * 4096 + lane;
#pragma unroll 4
    for (int jj = 0; jj < 64; ++jj) {
      float ev = ep[jj * 64];  // coalesced 256B/wave
      float xv = xp[jj * 64];
      float4 p = *(const float4*)(s_p + (w * 64 + jj) * 4);  // uniform -> broadcast
      ae[0] += p.x * ev; ae[1] += p.y * ev; ae[2] += p.z * ev; ae[3] += p.w * ev;
      px[0] += p.x * xv; px[1] += p.y * xv; px[2] += p.z * xv; px[3] += p.w * xv;
    }
#pragma unroll
    for (int hl = 0; hl < 4; ++hl) {
      atomicAdd(&s_ae[hl * 64 + lane], ae[hl]);  // disjoint addrs in-wave
      atomicAdd(&s_px[hl * 64 + lane], px[hl]);
    }
  }
  __syncthreads();

  // ---- fold softmax normalization
  if (t < 256) s_ae[t] *= s_inv[t >> 6];
  else if (t < 512) s_px[t - 256] *= s_inv[(t - 256) >> 6];
  __syncthreads();

  // ---- Epilogue (scratch aliases the now-dead s_p)
  float* s_eb  = s_p;        // 512 floats
  float* s_emb = s_p + 512;  // 128 floats
  float* s_op  = s_p + 768;  // 512 floats
  {
    const int nd = t & 127, ch = t >> 7, hl = nd >> 5;
    const int gnd = hg * 128 + nd;
    float emb = 0;
    const int cb = ch * 16;
#pragma unroll
    for (int c = cb; c < cb + 16; ++c)
      emb += s_ae[hl * 64 + c] * We[c * 256 + gnd] + s_px[hl * 64 + c] * Wv[c * 256 + gnd];
    s_eb[ch * 128 + nd] = emb;
  }
  __syncthreads();
  if (t < 128) s_emb[t] = s_eb[t] + s_eb[128 + t] + s_eb[256 + t] + s_eb[384 + t];
  __syncthreads();
  {
    const int o = t & 63, mc = t >> 6;
    float oo = 0;
#pragma unroll
    for (int m2 = mc * 16; m2 < mc * 16 + 16; ++m2)
      oo += s_emb[m2] * Wo[(hg * 128 + m2) * 64 + o];
    s_op[mc * 64 + o] = oo;
  }
  __syncthreads();
  if (t < 64) {
    float r = 0;
#pragma unroll
    for (int w2 = 0; w2 < 8; ++w2) r += s_op[w2 * 64 + t];
    if (hg == 0) r += bo[t];
    atomicAdd(&out[i * 64 + t], r);  // out pre-zeroed by memset
  }
}

extern "C" void kernel_launch(void* const* d_in, const int* in_sizes, int n_in,
                              void* d_out, int out_size, void* d_ws, size_t ws_size,
                              hipStream_t stream) {
  const float* x  = (const float*)d_in[0];
  const float* e  = (const float*)d_in[1];
  const float* Wq = (const float*)d_in[2];
  const float* Wk = (const float*)d_in[3];
  const float* Wv = (const float*)d_in[4];
  const float* We = (const float*)d_in[5];
  const float* Wo = (const float*)d_in[6];
  const float* bo = (const float*)d_in[7];
  float* out = (float*)d_out;

  hipMemsetAsync(d_out, 0, out_size, stream);
  hipLaunchKernelGGL(fused_kernel, dim3(1024), dim3(512), 0, stream,
                     e, x, Wq, Wk, We, Wv, Wo, bo, out);
}